// Round 4
// baseline (20053.658 us; speedup 1.0000x reference)
//
#include <hip/hip_runtime.h>

#define L_SEQ 4096
#define I_DIM 512
#define H_DIM 2048
#define O_DIM 512
#define NBLK  256
#define NTHR  512
#define BUFS  4          // >=3 makes tag-flow skew-safe with no barriers at all

typedef _Float16 h2 __attribute__((ext_vector_type(2)));
typedef float    f4 __attribute__((ext_vector_type(4)));
typedef unsigned int       u32;
typedef unsigned long long u64;
typedef u32 u32x4 __attribute__((ext_vector_type(4)));

struct __attribute__((aligned(16))) H4 { h2 v[4]; };

#define ALOAD32(p)     __hip_atomic_load((p), __ATOMIC_RELAXED, __HIP_MEMORY_SCOPE_AGENT)
#define ASTORE32(p, v) __hip_atomic_store((p), (v), __ATOMIC_RELAXED, __HIP_MEMORY_SCOPE_AGENT)
#define ALOAD64(p)     __hip_atomic_load((p), __ATOMIC_RELAXED, __HIP_MEMORY_SCOPE_AGENT)
#define ASTORE64(p, v) __hip_atomic_store((p), (v), __ATOMIC_RELAXED, __HIP_MEMORY_SCOPE_AGENT)

// One 16B device-coherent (L1+L2-bypass) load: 4 tagged dwords per transaction.
// Per-dword HW atomicity is enough — each dword carries its own tag.
__device__ __forceinline__ u32x4 mall_load16(const u32* p) {
  u32x4 r;
  asm volatile("global_load_dwordx4 %0, %1, off sc0 sc1\n\t"
               "s_waitcnt vmcnt(0)"
               : "=v"(r) : "v"(p) : "memory");
  return r;
}

__device__ __forceinline__ float fdot2_(h2 a, h2 b, float c) {
#if __has_builtin(__builtin_amdgcn_fdot2)
  return __builtin_amdgcn_fdot2(a, b, c, false);
#else
  return c + (float)a[0] * (float)b[0] + (float)a[1] * (float)b[1];
#endif
}

__device__ __forceinline__ float fast_sigmoid(float x) {
  // 1/(1+e^-x) via v_exp + v_rcp; rel err ~1e-5, negligible vs f16 h quantization
  return __builtin_amdgcn_rcpf(1.f + __expf(-x));
}
__device__ __forceinline__ float fast_tanh(float x) {
  float xc = fminf(fmaxf(x, -15.f), 15.f);
  float e2 = __expf(2.f * xc);
  return (e2 - 1.f) * __builtin_amdgcn_rcpf(e2 + 1.f);
}

// pack {tag16 | f16(h)} into one atomically-stored dword: the tag IS the flag.
__device__ __forceinline__ u32 packh(u32 tag, float v) {
  union { _Float16 h; unsigned short u; } c; c.h = (_Float16)v;
  return (tag << 16) | (u32)c.u;
}
__device__ __forceinline__ float f16bits_to_f32(u32 w) {
  union { unsigned short u; _Float16 h; } c; c.u = (unsigned short)(w & 0xffff);
  return (float)c.h;
}
__device__ __forceinline__ u64 pack64(u32 tag, float v) {
  union { float f; u32 u; } c; c.f = v;
  return ((u64)tag << 32) | c.u;
}
__device__ __forceinline__ float val64(u64 pk) {
  union { u32 u; float f; } c; c.u = (u32)pk; return c.f;
}
__device__ __forceinline__ u32 tag64(u64 pk) { return (u32)(pk >> 32); }

struct WRegs {
  h2 w[3][5][4];     // [gate r/z/n][k-segment 0..4][pair]  seg0 = W_ih, seg1..4 = W_hh
  float bi[3], bh[3];
};

__device__ __forceinline__ void load_weights(WRegs& W, int j, int lane,
    const float* __restrict__ w_ih, const float* __restrict__ w_hh,
    const float* __restrict__ b_ih, const float* __restrict__ b_hh) {
#pragma unroll
  for (int g = 0; g < 3; ++g) {
    const float* rih = w_ih + ((size_t)g * H_DIM + j) * I_DIM + lane * 8;
#pragma unroll
    for (int hh = 0; hh < 2; ++hh) {
      f4 a = *(const f4*)(rih + 4 * hh);
      W.w[g][0][2*hh+0] = h2{(_Float16)a[0], (_Float16)a[1]};
      W.w[g][0][2*hh+1] = h2{(_Float16)a[2], (_Float16)a[3]};
    }
    const float* rhh = w_hh + ((size_t)g * H_DIM + j) * H_DIM + lane * 8;
#pragma unroll
    for (int s = 1; s < 5; ++s) {
#pragma unroll
      for (int hh = 0; hh < 2; ++hh) {
        f4 a = *(const f4*)(rhh + (s - 1) * 512 + 4 * hh);
        W.w[g][s][2*hh+0] = h2{(_Float16)a[0], (_Float16)a[1]};
        W.w[g][s][2*hh+1] = h2{(_Float16)a[2], (_Float16)a[3]};
      }
    }
    W.bi[g] = b_ih[g * H_DIM + j];
    W.bh[g] = b_hh[g * H_DIM + j];
  }
}

// Tag-synchronized h staging: each thread polls ONE dwordx4 (4 tagged h words),
// then drops the f16 payloads into LDS. Data arrival IS the barrier.
__device__ __forceinline__ void stage4(_Float16* lbuf, const u32* p, u32 tag, int tid) {
  u32x4 v = mall_load16(p);
  while ((((v.x >> 16) ^ tag) | ((v.y >> 16) ^ tag) |
          ((v.z >> 16) ^ tag) | ((v.w >> 16) ^ tag)) != 0u) {
    __builtin_amdgcn_s_sleep(1);
    v = mall_load16(p);
  }
  *(u32*)(lbuf + tid * 4)     = (v.x & 0xffffu) | (v.y << 16);
  *(u32*)(lbuf + tid * 4 + 2) = (v.z & 0xffffu) | (v.w << 16);
}

__device__ __forceinline__ void dot_h(const WRegs& W, const _Float16* lbuf, int lane,
                                      float& ar, float& az, float& anh) {
#pragma unroll
  for (int s = 1; s < 5; ++s) {
    H4 hh = *(const H4*)(lbuf + (s - 1) * 512 + lane * 8);
#pragma unroll
    for (int q = 0; q < 4; ++q) {
      ar  = fdot2_(W.w[0][s][q], hh.v[q], ar);
      az  = fdot2_(W.w[1][s][q], hh.v[q], az);
      anh = fdot2_(W.w[2][s][q], hh.v[q], anh);
    }
  }
}

__device__ __forceinline__ void wave_red4(float& a, float& b, float& c, float& d) {
#pragma unroll
  for (int off = 32; off > 0; off >>= 1) {
    a += __shfl_xor(a, off, 64);
    b += __shfl_xor(b, off, 64);
    c += __shfl_xor(c, off, 64);
    d += __shfl_xor(d, off, 64);
  }
}

__global__ void __launch_bounds__(NTHR, 2) rnn_persistent(
    const float* __restrict__ input_,
    const float* __restrict__ ewih, const float* __restrict__ ewhh,
    const float* __restrict__ ebih, const float* __restrict__ ebhh,
    const float* __restrict__ dwih, const float* __restrict__ dwhh,
    const float* __restrict__ dbih, const float* __restrict__ dbhh,
    const float* __restrict__ h2ow, const float* __restrict__ h2ob,
    float* __restrict__ out, char* __restrict__ ws, int tdec)
{
  __shared__ alignas(16) _Float16 h_lds[2 * H_DIM];   // double buffer (parity of t)
  __shared__ float redm[8], reds[8];
  __shared__ int   sidx[8];
  __shared__ int   idx_sh;

  u32* hexch  = (u32*)ws;                    // BUFS * 2048 * 4B = 32 KB
  u64* logits = (u64*)(ws + BUFS * H_DIM * 4);
  u64* idxp   = (u64*)(ws + BUFS * H_DIM * 4 + O_DIM * 8);

  const int tid  = threadIdx.x;
  const int lane = tid & 63;
  const int wid  = tid >> 6;
  const int blk  = blockIdx.x;
  const int j    = blk * 8 + wid;     // hidden unit owned by this wave

  WRegs W;
  load_weights(W, j, lane, ewih, ewhh, ebih, ebhh);
  float brz0 = W.bi[0] + W.bh[0];
  float brz1 = W.bi[1] + W.bh[1];

  float hold = 0.f;   // exact fp32 carry of h_j

  // ---------------- encoder ----------------
  // iter t: consume h(t) [tag t, slot t%BUFS], produce h(t+1) [tag t+1].
  // memset gives {tag0, 0.0f16} = exactly h(0)=0 for t=0.
  // No trailing barrier: stage4(t+2) can only pass once all waves finished
  // iter t+1, which (program order) follows their reads of LDS buffer t&1.
  for (u32 t = 0; t < L_SEQ; ++t) {
    _Float16* lbuf = h_lds + (t & 1) * H_DIM;
    const float* xr = input_ + (size_t)t * I_DIM + lane * 8;
    f4 xa = *(const f4*)xr;                 // issued before the poll; latency hides
    f4 xb = *(const f4*)(xr + 4);

    stage4(lbuf, hexch + (t % BUFS) * H_DIM + tid * 4, t & 0xffffu, tid);

    // x-part of the dot: hides in barrier-arrival skew
    h2 xv[4] = { h2{(_Float16)xa[0], (_Float16)xa[1]}, h2{(_Float16)xa[2], (_Float16)xa[3]},
                 h2{(_Float16)xb[0], (_Float16)xb[1]}, h2{(_Float16)xb[2], (_Float16)xb[3]} };
    float ar = 0.f, az = 0.f, anx = 0.f, anh = 0.f;
#pragma unroll
    for (int q = 0; q < 4; ++q) {
      ar  = fdot2_(W.w[0][0][q], xv[q], ar);
      az  = fdot2_(W.w[1][0][q], xv[q], az);
      anx = fdot2_(W.w[2][0][q], xv[q], anx);
    }
    __syncthreads();

    dot_h(W, lbuf, lane, ar, az, anh);
    wave_red4(ar, az, anx, anh);

    float r = fast_sigmoid(ar + brz0);
    float z = fast_sigmoid(az + brz1);
    float n = fast_tanh(anx + W.bi[2] + r * (anh + W.bh[2]));
    hold = (1.f - z) * n + z * hold;
    if (lane == 0)
      ASTORE32(&hexch[((t + 1) % BUFS) * H_DIM + j], packh((t + 1) & 0xffffu, hold));
  }

  // ---------------- decoder ----------------
  load_weights(W, j, lane, dwih, dwhh, dbih, dbhh);
  brz0 = W.bi[0] + W.bh[0];
  brz1 = W.bi[1] + W.bh[1];
  __syncthreads();

  for (int d = 0; d < tdec; ++d) {
    const u32 t = L_SEQ + (u32)d;
    _Float16* lbuf = h_lds + (t & 1) * H_DIM;

    if (tid == 0) {
      int ix = -1;
      if (d > 0) {                          // poll one-hot index {tag d}
        u64 pk = ALOAD64(idxp);
        while (tag64(pk) != (u32)d) { __builtin_amdgcn_s_sleep(1); pk = ALOAD64(idxp); }
        ix = (int)(u32)pk;
      }
      idx_sh = ix;
    }
    stage4(lbuf, hexch + (t % BUFS) * H_DIM + tid * 4, t & 0xffffu, tid);
    __syncthreads();
    const int idx = idx_sh;

    float ar = 0.f, az = 0.f, anx = 0.f, anh = 0.f;
    if (idx >= 0 && lane == (idx >> 3)) {
      const int qq = (idx & 7) >> 1;
      const int pp = idx & 1;
#pragma unroll
      for (int q = 0; q < 4; ++q) if (q == qq) {
        ar  += pp ? (float)W.w[0][0][q][1] : (float)W.w[0][0][q][0];
        az  += pp ? (float)W.w[1][0][q][1] : (float)W.w[1][0][q][0];
        anx += pp ? (float)W.w[2][0][q][1] : (float)W.w[2][0][q][0];
      }
    }
    dot_h(W, lbuf, lane, ar, az, anh);
    wave_red4(ar, az, anx, anh);

    float r = fast_sigmoid(ar + brz0);
    float z = fast_sigmoid(az + brz1);
    float n = fast_tanh(anx + W.bi[2] + r * (anh + W.bh[2]));
    hold = (1.f - z) * n + z * hold;
    if (lane == 0)
      ASTORE32(&hexch[((t + 1) % BUFS) * H_DIM + j], packh((t + 1) & 0xffffu, hold));

    // ---- logits: rows 2*blk, 2*blk+1; consume h(t+1) via tagged dwordx4s ----
    {
      const int row = 2 * blk + (tid >> 8);
      const int kk  = (tid & 255) * 8;
      const float* wrow = h2ow + (size_t)row * H_DIM + kk;
      f4 wa = *(const f4*)wrow, wb = *(const f4*)(wrow + 4);
      const u32* hp = hexch + ((t + 1) % BUFS) * H_DIM + kk;
      const u32 htag = (t + 1) & 0xffffu;
      u32x4 g0 = mall_load16(hp), g1 = mall_load16(hp + 4);
      for (;;) {
        u32 bad = ((g0.x >> 16) ^ htag) | ((g0.y >> 16) ^ htag)
                | ((g0.z >> 16) ^ htag) | ((g0.w >> 16) ^ htag)
                | ((g1.x >> 16) ^ htag) | ((g1.y >> 16) ^ htag)
                | ((g1.z >> 16) ^ htag) | ((g1.w >> 16) ^ htag);
        if (!bad) break;
        __builtin_amdgcn_s_sleep(1);
        g0 = mall_load16(hp); g1 = mall_load16(hp + 4);
      }
      float s = wa[0]*f16bits_to_f32(g0.x) + wa[1]*f16bits_to_f32(g0.y)
              + wa[2]*f16bits_to_f32(g0.z) + wa[3]*f16bits_to_f32(g0.w)
              + wb[0]*f16bits_to_f32(g1.x) + wb[1]*f16bits_to_f32(g1.y)
              + wb[2]*f16bits_to_f32(g1.z) + wb[3]*f16bits_to_f32(g1.w);
#pragma unroll
      for (int off = 32; off > 0; off >>= 1) s += __shfl_xor(s, off, 64);
      if (lane == 0) redm[wid] = s;
      __syncthreads();
      if (tid == 0)
        ASTORE64(&logits[2 * blk],
                 pack64((u32)(d + 1), redm[0] + redm[1] + redm[2] + redm[3] + h2ob[2 * blk]));
      if (tid == 256)
        ASTORE64(&logits[2 * blk + 1],
                 pack64((u32)(d + 1), redm[4] + redm[5] + redm[6] + redm[7] + h2ob[2 * blk + 1]));
    }
    __syncthreads();

    // ---- log-softmax + argmax on block 0 (consumes tagged logits) ----
    if (blk == 0) {
      u64 pk = ALOAD64(&logits[tid]);
      while (tag64(pk) != (u32)(d + 1)) { __builtin_amdgcn_s_sleep(1); pk = ALOAD64(&logits[tid]); }
      float v = val64(pk);
      float m = v; int mi = tid;
#pragma unroll
      for (int off = 32; off > 0; off >>= 1) {
        float om = __shfl_xor(m, off, 64);
        int   oi = __shfl_xor(mi, off, 64);
        if (om > m || (om == m && oi < mi)) { m = om; mi = oi; }
      }
      if (lane == 0) { redm[wid] = m; sidx[wid] = mi; }
      __syncthreads();
      float M = redm[0]; int MI = sidx[0];
#pragma unroll
      for (int w2 = 1; w2 < 8; ++w2)
        if (redm[w2] > M || (redm[w2] == M && sidx[w2] < MI)) { M = redm[w2]; MI = sidx[w2]; }
      float ss = __expf(v - M);
#pragma unroll
      for (int off = 32; off > 0; off >>= 1) ss += __shfl_xor(ss, off, 64);
      if (lane == 0) reds[wid] = ss;
      __syncthreads();
      float S = reds[0] + reds[1] + reds[2] + reds[3]
              + reds[4] + reds[5] + reds[6] + reds[7];
      out[(size_t)d * O_DIM + tid] = v - M - __logf(S);
      if (tid == 0)
        ASTORE64(idxp, pack64((u32)(d + 1), (u32)MI));
    }
    __syncthreads();   // LDS reuse guard (decoder only; negligible at 30 steps)
  }
}

extern "C" void kernel_launch(void* const* d_in, const int* in_sizes, int n_in,
                              void* d_out, int out_size, void* d_ws, size_t ws_size,
                              hipStream_t stream) {
  const float* input_ = (const float*)d_in[0];
  const float* ewih   = (const float*)d_in[1];
  const float* ewhh   = (const float*)d_in[2];
  const float* ebih   = (const float*)d_in[3];
  const float* ebhh   = (const float*)d_in[4];
  const float* dwih   = (const float*)d_in[5];
  const float* dwhh   = (const float*)d_in[6];
  const float* dbih   = (const float*)d_in[7];
  const float* dbhh   = (const float*)d_in[8];
  const float* h2ow   = (const float*)d_in[9];
  const float* h2ob   = (const float*)d_in[10];
  float* out = (float*)d_out;
  char*  ws  = (char*)d_ws;
  int tdec = out_size / O_DIM;   // 30

  // zero the exchange region: tags reset to 0 (= valid h(0)=0 for iter 0)
  hipMemsetAsync(d_ws, 0, BUFS * H_DIM * 4 + O_DIM * 8 + 64, stream);

  void* args[] = { (void*)&input_, (void*)&ewih, (void*)&ewhh, (void*)&ebih, (void*)&ebhh,
                   (void*)&dwih, (void*)&dwhh, (void*)&dbih, (void*)&dbhh,
                   (void*)&h2ow, (void*)&h2ob, (void*)&out, (void*)&ws, (void*)&tdec };
  hipLaunchCooperativeKernel((void*)rnn_persistent, dim3(NBLK), dim3(NTHR),
                             args, 0, stream);
}

// Round 7
// 17837.979 us; speedup vs baseline: 1.1242x; 1.1242x over previous
//
#include <hip/hip_runtime.h>

#define L_SEQ 4096
#define I_DIM 512
#define H_DIM 2048
#define O_DIM 512
#define NBLK  256
#define NTHR  512
#define BUFS  4          // >=3 keeps tag-flow reuse skew-safe without barriers
#define RSTR (BUFS * H_DIM)   // u32 stride between mailbox replicas (32 KB)

// ws layout: [0:4K) logits u64[512] | [4K:4K+64) idx | [8K:...) replicas R x 32KB

typedef _Float16 h2 __attribute__((ext_vector_type(2)));
typedef float    f4 __attribute__((ext_vector_type(4)));
typedef unsigned int       u32;
typedef unsigned long long u64;
typedef u32 u32x4 __attribute__((ext_vector_type(4)));

struct __attribute__((aligned(16))) H4 { h2 v[4]; };

#define ALOAD64(p)     __hip_atomic_load((p), __ATOMIC_RELAXED, __HIP_MEMORY_SCOPE_AGENT)
#define ASTORE64(p, v) __hip_atomic_store((p), (v), __ATOMIC_RELAXED, __HIP_MEMORY_SCOPE_AGENT)
#define ALOAD32(p)     __hip_atomic_load((p), __ATOMIC_RELAXED, __HIP_MEMORY_SCOPE_AGENT)
#define ASTORE32(p, v) __hip_atomic_store((p), (v), __ATOMIC_RELAXED, __HIP_MEMORY_SCOPE_AGENT)

// Sound tagged 16B device-coherent load: the load AND its wait live in ONE asm
// block, so no in-flight register hazards (the r6 pipelined variant was UB).
__device__ __forceinline__ u32x4 mall_load16(const u32* p) {
  u32x4 r;
  asm volatile("global_load_dwordx4 %0, %1, off sc0 sc1\n\t"
               "s_waitcnt vmcnt(0)"
               : "=v"(r) : "v"(p) : "memory");
  return r;
}

__device__ __forceinline__ u32 tagbad(u32x4 v, u32 tag) {
  return ((v.x >> 16) ^ tag) | ((v.y >> 16) ^ tag) |
         ((v.z >> 16) ^ tag) | ((v.w >> 16) ^ tag);
}

__device__ __forceinline__ float fdot2_(h2 a, h2 b, float c) {
#if __has_builtin(__builtin_amdgcn_fdot2)
  return __builtin_amdgcn_fdot2(a, b, c, false);
#else
  return c + (float)a[0] * (float)b[0] + (float)a[1] * (float)b[1];
#endif
}
__device__ __forceinline__ float fast_sigmoid(float x) {
  return __builtin_amdgcn_rcpf(1.f + __expf(-x));
}
__device__ __forceinline__ float fast_tanh(float x) {
  float xc = fminf(fmaxf(x, -15.f), 15.f);
  float e2 = __expf(2.f * xc);
  return (e2 - 1.f) * __builtin_amdgcn_rcpf(e2 + 1.f);
}

__device__ __forceinline__ u32 packh(u32 tag, float v) {
  union { _Float16 h; unsigned short u; } c; c.h = (_Float16)v;
  return (tag << 16) | (u32)c.u;
}
__device__ __forceinline__ float f16bits_to_f32(u32 w) {
  union { unsigned short u; _Float16 h; } c; c.u = (unsigned short)(w & 0xffff);
  return (float)c.h;
}
__device__ __forceinline__ u64 pack64(u32 tag, float v) {
  union { float f; u32 u; } c; c.f = v;
  return ((u64)tag << 32) | c.u;
}
__device__ __forceinline__ float val64(u64 pk) {
  union { u32 u; float f; } c; c.u = (u32)pk; return c.f;
}
__device__ __forceinline__ u32 tag64(u64 pk) { return (u32)(pk >> 32); }

struct WRegs {
  h2 w[3][5][4];     // [gate r/z/n][k-seg 0..4][pair]  seg0 = W_ih, seg1..4 = W_hh
  float bi[3], bh[3];
};

__device__ __forceinline__ void load_weights(WRegs& W, int j, int lane,
    const float* __restrict__ w_ih, const float* __restrict__ w_hh,
    const float* __restrict__ b_ih, const float* __restrict__ b_hh) {
#pragma unroll
  for (int g = 0; g < 3; ++g) {
    const float* rih = w_ih + ((size_t)g * H_DIM + j) * I_DIM + lane * 8;
#pragma unroll
    for (int hh = 0; hh < 2; ++hh) {
      f4 a = *(const f4*)(rih + 4 * hh);
      W.w[g][0][2*hh+0] = h2{(_Float16)a[0], (_Float16)a[1]};
      W.w[g][0][2*hh+1] = h2{(_Float16)a[2], (_Float16)a[3]};
    }
    const float* rhh = w_hh + ((size_t)g * H_DIM + j) * H_DIM + lane * 8;
#pragma unroll
    for (int s = 1; s < 5; ++s) {
#pragma unroll
      for (int hh = 0; hh < 2; ++hh) {
        f4 a = *(const f4*)(rhh + (s - 1) * 512 + 4 * hh);
        W.w[g][s][2*hh+0] = h2{(_Float16)a[0], (_Float16)a[1]};
        W.w[g][s][2*hh+1] = h2{(_Float16)a[2], (_Float16)a[3]};
      }
    }
    W.bi[g] = b_ih[g * H_DIM + j];
    W.bh[g] = b_hh[g * H_DIM + j];
  }
}

// Tag-synchronized h staging from this block's replica: each thread polls one
// 16B granule (4 tagged words), then drops the f16 payloads into LDS.
__device__ __forceinline__ void stage4(_Float16* lbuf, const u32* p, u32 tag, int tid) {
  u32x4 v = mall_load16(p);
  while (tagbad(v, tag)) {
    __builtin_amdgcn_s_sleep(1);
    v = mall_load16(p);
  }
  u64 pk = (u64)((v.x & 0xffffu) | (v.y << 16))
         | ((u64)((v.z & 0xffffu) | (v.w << 16)) << 32);
  *(u64*)(lbuf + tid * 4) = pk;
}

__device__ __forceinline__ void dot_h(const WRegs& W, const _Float16* lbuf, int lane,
                                      float& ar, float& az, float& anh) {
#pragma unroll
  for (int s = 1; s < 5; ++s) {
    H4 hh = *(const H4*)(lbuf + (s - 1) * 512 + lane * 8);
#pragma unroll
    for (int q = 0; q < 4; ++q) {
      ar  = fdot2_(W.w[0][s][q], hh.v[q], ar);
      az  = fdot2_(W.w[1][s][q], hh.v[q], az);
      anh = fdot2_(W.w[2][s][q], hh.v[q], anh);
    }
  }
}

// butterfly: ALL lanes end with the full sum (enables multi-lane multicast store)
__device__ __forceinline__ void wave_red4(float& a, float& b, float& c, float& d) {
#pragma unroll
  for (int off = 32; off > 0; off >>= 1) {
    a += __shfl_xor(a, off, 64);
    b += __shfl_xor(b, off, 64);
    c += __shfl_xor(c, off, 64);
    d += __shfl_xor(d, off, 64);
  }
}

__global__ void __launch_bounds__(NTHR, 2) rnn_persistent(
    const float* __restrict__ input_,
    const float* __restrict__ ewih, const float* __restrict__ ewhh,
    const float* __restrict__ ebih, const float* __restrict__ ebhh,
    const float* __restrict__ dwih, const float* __restrict__ dwhh,
    const float* __restrict__ dbih, const float* __restrict__ dbhh,
    const float* __restrict__ h2ow, const float* __restrict__ h2ob,
    float* __restrict__ out, char* __restrict__ ws, int tdec, int R)
{
  __shared__ alignas(16) _Float16 h_lds[2 * H_DIM];   // double buffer (parity of t)
  __shared__ float redm[8], reds[8];
  __shared__ int   sidx[8];
  __shared__ int   idx_sh;

  u64* logits = (u64*)ws;
  u64* idxp   = (u64*)(ws + 4096);
  u32* gex    = (u32*)(ws + 8192);                 // replica 0 base

  const int tid  = threadIdx.x;
  const int lane = tid & 63;
  const int wid  = tid >> 6;
  const int blk  = blockIdx.x;
  const int j    = blk * 8 + wid;                  // hidden unit owned by this wave
  const u32* gexr = gex + (size_t)(blk & (R - 1)) * RSTR;  // replica this block polls

  WRegs W;
  load_weights(W, j, lane, ewih, ewhh, ebih, ebhh);
  float brz0 = W.bi[0] + W.bh[0];
  float brz1 = W.bi[1] + W.bh[1];

  float hold = 0.f;   // exact fp32 carry of h_j

  // ---------------- encoder ----------------
  // iter t: consume h(t) [tag t, slot t&3] from own replica; produce h(t+1)
  // [tag t+1] into ALL replicas (lanes 0..R-1 multicast — wave_red4 leaves the
  // reduced value in every lane). memset gives {tag0,0.0f16} = valid h(0)=0.
  for (u32 t = 0; t < L_SEQ; ++t) {
    _Float16* lbuf = h_lds + (t & 1) * H_DIM;
    const float* xr = input_ + (size_t)t * I_DIM + lane * 8;
    f4 xa = *(const f4*)xr;                  // prefetch; latency hides under poll
    f4 xb = *(const f4*)(xr + 4);

    stage4(lbuf, gexr + (t & (BUFS - 1)) * H_DIM + tid * 4, t & 0xffffu, tid);

    h2 xv[4] = { h2{(_Float16)xa[0], (_Float16)xa[1]}, h2{(_Float16)xa[2], (_Float16)xa[3]},
                 h2{(_Float16)xb[0], (_Float16)xb[1]}, h2{(_Float16)xb[2], (_Float16)xb[3]} };
    float ar = 0.f, az = 0.f, anx = 0.f, anh = 0.f;
#pragma unroll
    for (int q = 0; q < 4; ++q) {
      ar  = fdot2_(W.w[0][0][q], xv[q], ar);
      az  = fdot2_(W.w[1][0][q], xv[q], az);
      anx = fdot2_(W.w[2][0][q], xv[q], anx);
    }
    __syncthreads();

    dot_h(W, lbuf, lane, ar, az, anh);
    wave_red4(ar, az, anx, anh);

    float r = fast_sigmoid(ar + brz0);
    float z = fast_sigmoid(az + brz1);
    float n = fast_tanh(anx + W.bi[2] + r * (anh + W.bh[2]));
    hold = (1.f - z) * n + z * hold;
    {   // multicast: one store instruction, R active lanes, R replica regions
      u32 pk = packh((t + 1) & 0xffffu, hold);
      u32* dst = (u32*)gex + (size_t)lane * RSTR + ((t + 1) & (BUFS - 1)) * H_DIM + j;
      if (lane < R) ASTORE32(dst, pk);
    }
  }

  // ---------------- decoder ----------------
  load_weights(W, j, lane, dwih, dwhh, dbih, dbhh);
  brz0 = W.bi[0] + W.bh[0];
  brz1 = W.bi[1] + W.bh[1];
  __syncthreads();

  for (int d = 0; d < tdec; ++d) {
    const u32 t = L_SEQ + (u32)d;
    _Float16* lbuf = h_lds + (t & 1) * H_DIM;

    if (tid == 0) {
      int ix = -1;
      if (d > 0) {                          // poll one-hot index {tag d}
        u64 pk = ALOAD64(idxp);
        while (tag64(pk) != (u32)d) { __builtin_amdgcn_s_sleep(1); pk = ALOAD64(idxp); }
        ix = (int)(u32)pk;
      }
      idx_sh = ix;
    }
    stage4(lbuf, gexr + (t & (BUFS - 1)) * H_DIM + tid * 4, t & 0xffffu, tid);
    __syncthreads();
    const int idx = idx_sh;

    float ar = 0.f, az = 0.f, anx = 0.f, anh = 0.f;
    if (idx >= 0 && lane == (idx >> 3)) {
      const int qq = (idx & 7) >> 1;
      const int pp = idx & 1;
#pragma unroll
      for (int q = 0; q < 4; ++q) if (q == qq) {
        ar  += pp ? (float)W.w[0][0][q][1] : (float)W.w[0][0][q][0];
        az  += pp ? (float)W.w[1][0][q][1] : (float)W.w[1][0][q][0];
        anx += pp ? (float)W.w[2][0][q][1] : (float)W.w[2][0][q][0];
      }
    }
    dot_h(W, lbuf, lane, ar, az, anh);
    wave_red4(ar, az, anx, anh);

    float r = fast_sigmoid(ar + brz0);
    float z = fast_sigmoid(az + brz1);
    float n = fast_tanh(anx + W.bi[2] + r * (anh + W.bh[2]));
    hold = (1.f - z) * n + z * hold;
    {
      u32 pk = packh((t + 1) & 0xffffu, hold);
      u32* dst = (u32*)gex + (size_t)lane * RSTR + ((t + 1) & (BUFS - 1)) * H_DIM + j;
      if (lane < R) ASTORE32(dst, pk);
    }

    // ---- logits: rows 2*blk, 2*blk+1; consume h(t+1) from own replica ----
    {
      const int row = 2 * blk + (tid >> 8);
      const int kk  = (tid & 255) * 8;
      const float* wrow = h2ow + (size_t)row * H_DIM + kk;
      f4 wa = *(const f4*)wrow, wb = *(const f4*)(wrow + 4);
      const u32* hp = gexr + ((t + 1) & (BUFS - 1)) * H_DIM + kk;
      const u32 htag = (t + 1) & 0xffffu;
      u32x4 g0 = mall_load16(hp), g1 = mall_load16(hp + 4);
      while (tagbad(g0, htag) | tagbad(g1, htag)) {
        __builtin_amdgcn_s_sleep(1);
        g0 = mall_load16(hp); g1 = mall_load16(hp + 4);
      }
      float s = wa[0]*f16bits_to_f32(g0.x) + wa[1]*f16bits_to_f32(g0.y)
              + wa[2]*f16bits_to_f32(g0.z) + wa[3]*f16bits_to_f32(g0.w)
              + wb[0]*f16bits_to_f32(g1.x) + wb[1]*f16bits_to_f32(g1.y)
              + wb[2]*f16bits_to_f32(g1.z) + wb[3]*f16bits_to_f32(g1.w);
#pragma unroll
      for (int off = 32; off > 0; off >>= 1) s += __shfl_xor(s, off, 64);
      if (lane == 0) redm[wid] = s;
      __syncthreads();
      if (tid == 0)
        ASTORE64(&logits[2 * blk],
                 pack64((u32)(d + 1), redm[0] + redm[1] + redm[2] + redm[3] + h2ob[2 * blk]));
      if (tid == 256)
        ASTORE64(&logits[2 * blk + 1],
                 pack64((u32)(d + 1), redm[4] + redm[5] + redm[6] + redm[7] + h2ob[2 * blk + 1]));
    }
    __syncthreads();

    // ---- log-softmax + argmax on block 0 (consumes tagged logits) ----
    if (blk == 0) {
      u64 pk = ALOAD64(&logits[tid]);
      while (tag64(pk) != (u32)(d + 1)) { __builtin_amdgcn_s_sleep(1); pk = ALOAD64(&logits[tid]); }
      float v = val64(pk);
      float m = v; int mi = tid;
#pragma unroll
      for (int off = 32; off > 0; off >>= 1) {
        float om = __shfl_xor(m, off, 64);
        int   oi = __shfl_xor(mi, off, 64);
        if (om > m || (om == m && oi < mi)) { m = om; mi = oi; }
      }
      if (lane == 0) { redm[wid] = m; sidx[wid] = mi; }
      __syncthreads();
      float M = redm[0]; int MI = sidx[0];
#pragma unroll
      for (int w2 = 1; w2 < 8; ++w2)
        if (redm[w2] > M || (redm[w2] == M && sidx[w2] < MI)) { M = redm[w2]; MI = sidx[w2]; }
      float ss = __expf(v - M);
#pragma unroll
      for (int off = 32; off > 0; off >>= 1) ss += __shfl_xor(ss, off, 64);
      if (lane == 0) reds[wid] = ss;
      __syncthreads();
      float S = reds[0] + reds[1] + reds[2] + reds[3]
              + reds[4] + reds[5] + reds[6] + reds[7];
      out[(size_t)d * O_DIM + tid] = v - M - __logf(S);
      if (tid == 0)
        ASTORE64(idxp, pack64((u32)(d + 1), (u32)MI));
    }
    __syncthreads();   // LDS reuse guard (decoder only; negligible at 30 steps)
  }
}

extern "C" void kernel_launch(void* const* d_in, const int* in_sizes, int n_in,
                              void* d_out, int out_size, void* d_ws, size_t ws_size,
                              hipStream_t stream) {
  const float* input_ = (const float*)d_in[0];
  const float* ewih   = (const float*)d_in[1];
  const float* ewhh   = (const float*)d_in[2];
  const float* ebih   = (const float*)d_in[3];
  const float* ebhh   = (const float*)d_in[4];
  const float* dwih   = (const float*)d_in[5];
  const float* dwhh   = (const float*)d_in[6];
  const float* dbih   = (const float*)d_in[7];
  const float* dbhh   = (const float*)d_in[8];
  const float* h2ow   = (const float*)d_in[9];
  const float* h2ob   = (const float*)d_in[10];
  float* out = (float*)d_out;
  char*  ws  = (char*)d_ws;
  int tdec = out_size / O_DIM;   // 30

  // replica count from actual workspace size (R=1 degrades to the r3 design)
  int R = 1;
  if (ws_size >= 8192 + 32768) {
    size_t maxr = (ws_size - 8192) / 32768;
    while (R * 2 <= (int)(maxr < 8 ? maxr : 8)) R *= 2;
  }
  size_t zbytes = 8192 + (size_t)R * 32768;

  // zero logits+idx+replicas (tag0 == valid h(0)=0 in every replica)
  hipMemsetAsync(d_ws, 0, zbytes, stream);

  void* args[] = { (void*)&input_, (void*)&ewih, (void*)&ewhh, (void*)&ebih, (void*)&ebhh,
                   (void*)&dwih, (void*)&dwhh, (void*)&dbih, (void*)&dbhh,
                   (void*)&h2ow, (void*)&h2ob, (void*)&out, (void*)&ws, (void*)&tdec,
                   (void*)&R };
  hipLaunchCooperativeKernel((void*)rnn_persistent, dim3(NBLK), dim3(NTHR),
                             args, 0, stream);
}

// Round 8
// 12462.408 us; speedup vs baseline: 1.6091x; 1.4313x over previous
//
#include <hip/hip_runtime.h>

#define L_SEQ 4096
#define I_DIM 512
#define H_DIM 2048
#define O_DIM 512
#define NBLK  256
#define NTHR  512
#define BUFS  4          // >=3 keeps tag-flow reuse skew-safe without barriers
#define RSTR (BUFS * H_DIM)   // u32 stride between mailbox replicas (32 KB)

// ws layout: [0:4K) logits u64[512] | [4K:4K+64) idx | [8K:...) replicas R x 32KB

typedef _Float16 h2 __attribute__((ext_vector_type(2)));
typedef float    f4 __attribute__((ext_vector_type(4)));
typedef unsigned int       u32;
typedef unsigned long long u64;

struct __attribute__((aligned(16))) H4 { h2 v[4]; };

#define ALOAD64(p)     __hip_atomic_load((p), __ATOMIC_RELAXED, __HIP_MEMORY_SCOPE_AGENT)
#define ASTORE64(p, v) __hip_atomic_store((p), (v), __ATOMIC_RELAXED, __HIP_MEMORY_SCOPE_AGENT)
#define ALOAD32(p)     __hip_atomic_load((p), __ATOMIC_RELAXED, __HIP_MEMORY_SCOPE_AGENT)
#define ASTORE32(p, v) __hip_atomic_store((p), (v), __ATOMIC_RELAXED, __HIP_MEMORY_SCOPE_AGENT)

// Dual-generation pipelined tagged poll of one 16B granule (4 tagged dwords).
// ENTIRE spin loop lives in one asm block: loads, checks, reissues, and the
// final vmcnt(0) drain — no in-flight-register hazards (r6's bug). Detection
// quantum ~ RT/2. Wave proceeds when ALL lanes' granules carry `tag`.
// Re-reads of a ready granule are stable (slot rewritten only at t+BUFS).
__device__ __forceinline__ void poll_granule(const u32* p, u32 tag,
                                             u32& r0, u32& r1, u32& r2, u32& r3) {
  u32 a0,a1,a2,a3,b0,b1,b2,b3,t0,t1,t2,t3;
  asm volatile(
    "global_load_dword %[a0], %[ptr], off sc0 sc1\n\t"
    "global_load_dword %[a1], %[ptr], off offset:4 sc0 sc1\n\t"
    "global_load_dword %[a2], %[ptr], off offset:8 sc0 sc1\n\t"
    "global_load_dword %[a3], %[ptr], off offset:12 sc0 sc1\n\t"
    "global_load_dword %[b0], %[ptr], off sc0 sc1\n\t"
    "global_load_dword %[b1], %[ptr], off offset:4 sc0 sc1\n\t"
    "global_load_dword %[b2], %[ptr], off offset:8 sc0 sc1\n\t"
    "global_load_dword %[b3], %[ptr], off offset:12 sc0 sc1\n\t"
    "Lpoll_%=:\n\t"
    "s_waitcnt vmcnt(4)\n\t"                  // generation A landed (B in flight)
    "v_lshrrev_b32 %[t0], 16, %[a0]\n\t"
    "v_lshrrev_b32 %[t1], 16, %[a1]\n\t"
    "v_lshrrev_b32 %[t2], 16, %[a2]\n\t"
    "v_lshrrev_b32 %[t3], 16, %[a3]\n\t"
    "v_xor_b32 %[t0], %[tg], %[t0]\n\t"
    "v_xor_b32 %[t1], %[tg], %[t1]\n\t"
    "v_xor_b32 %[t2], %[tg], %[t2]\n\t"
    "v_xor_b32 %[t3], %[tg], %[t3]\n\t"
    "v_or_b32 %[t0], %[t0], %[t1]\n\t"
    "v_or_b32 %[t2], %[t2], %[t3]\n\t"
    "v_or_b32 %[t0], %[t0], %[t2]\n\t"
    "v_cmp_ne_u32 vcc, 0, %[t0]\n\t"
    "s_nop 4\n\t"                             // VCC->vccz hazard guard
    "s_cbranch_vccz LgoodA_%=\n\t"
    "global_load_dword %[a0], %[ptr], off sc0 sc1\n\t"
    "global_load_dword %[a1], %[ptr], off offset:4 sc0 sc1\n\t"
    "global_load_dword %[a2], %[ptr], off offset:8 sc0 sc1\n\t"
    "global_load_dword %[a3], %[ptr], off offset:12 sc0 sc1\n\t"
    "s_waitcnt vmcnt(4)\n\t"                  // generation B landed (A in flight)
    "v_lshrrev_b32 %[t0], 16, %[b0]\n\t"
    "v_lshrrev_b32 %[t1], 16, %[b1]\n\t"
    "v_lshrrev_b32 %[t2], 16, %[b2]\n\t"
    "v_lshrrev_b32 %[t3], 16, %[b3]\n\t"
    "v_xor_b32 %[t0], %[tg], %[t0]\n\t"
    "v_xor_b32 %[t1], %[tg], %[t1]\n\t"
    "v_xor_b32 %[t2], %[tg], %[t2]\n\t"
    "v_xor_b32 %[t3], %[tg], %[t3]\n\t"
    "v_or_b32 %[t0], %[t0], %[t1]\n\t"
    "v_or_b32 %[t2], %[t2], %[t3]\n\t"
    "v_or_b32 %[t0], %[t0], %[t2]\n\t"
    "v_cmp_ne_u32 vcc, 0, %[t0]\n\t"
    "s_nop 4\n\t"
    "s_cbranch_vccz LgoodB_%=\n\t"
    "global_load_dword %[b0], %[ptr], off sc0 sc1\n\t"
    "global_load_dword %[b1], %[ptr], off offset:4 sc0 sc1\n\t"
    "global_load_dword %[b2], %[ptr], off offset:8 sc0 sc1\n\t"
    "global_load_dword %[b3], %[ptr], off offset:12 sc0 sc1\n\t"
    "s_branch Lpoll_%=\n\t"
    "LgoodB_%=:\n\t"
    "v_mov_b32 %[a0], %[b0]\n\t"
    "v_mov_b32 %[a1], %[b1]\n\t"
    "v_mov_b32 %[a2], %[b2]\n\t"
    "v_mov_b32 %[a3], %[b3]\n\t"
    "LgoodA_%=:\n\t"
    "s_waitcnt vmcnt(0)"                      // drain strays before regs escape
    : [a0]"=&v"(a0), [a1]"=&v"(a1), [a2]"=&v"(a2), [a3]"=&v"(a3),
      [b0]"=&v"(b0), [b1]"=&v"(b1), [b2]"=&v"(b2), [b3]"=&v"(b3),
      [t0]"=&v"(t0), [t1]"=&v"(t1), [t2]"=&v"(t2), [t3]"=&v"(t3)
    : [ptr]"v"(p), [tg]"s"(tag)
    : "vcc", "memory");
  r0 = a0; r1 = a1; r2 = a2; r3 = a3;
}

__device__ __forceinline__ float fdot2_(h2 a, h2 b, float c) {
#if __has_builtin(__builtin_amdgcn_fdot2)
  return __builtin_amdgcn_fdot2(a, b, c, false);
#else
  return c + (float)a[0] * (float)b[0] + (float)a[1] * (float)b[1];
#endif
}
__device__ __forceinline__ float fast_sigmoid(float x) {
  return __builtin_amdgcn_rcpf(1.f + __expf(-x));
}
__device__ __forceinline__ float fast_tanh(float x) {
  float xc = fminf(fmaxf(x, -15.f), 15.f);
  float e2 = __expf(2.f * xc);
  return (e2 - 1.f) * __builtin_amdgcn_rcpf(e2 + 1.f);
}

__device__ __forceinline__ u32 packh(u32 tag, float v) {
  union { _Float16 h; unsigned short u; } c; c.h = (_Float16)v;
  return (tag << 16) | (u32)c.u;
}
__device__ __forceinline__ float f16bits_to_f32(u32 w) {
  union { unsigned short u; _Float16 h; } c; c.u = (unsigned short)(w & 0xffff);
  return (float)c.h;
}
__device__ __forceinline__ u64 pack64(u32 tag, float v) {
  union { float f; u32 u; } c; c.f = v;
  return ((u64)tag << 32) | c.u;
}
__device__ __forceinline__ float val64(u64 pk) {
  union { u32 u; float f; } c; c.u = (u32)pk; return c.f;
}
__device__ __forceinline__ u32 tag64(u64 pk) { return (u32)(pk >> 32); }

struct WRegs {
  h2 w[3][5][4];     // [gate r/z/n][k-seg 0..4][pair]  seg0 = W_ih, seg1..4 = W_hh
  float bi[3], bh[3];
};

__device__ __forceinline__ void load_weights(WRegs& W, int j, int lane,
    const float* __restrict__ w_ih, const float* __restrict__ w_hh,
    const float* __restrict__ b_ih, const float* __restrict__ b_hh) {
#pragma unroll
  for (int g = 0; g < 3; ++g) {
    const float* rih = w_ih + ((size_t)g * H_DIM + j) * I_DIM + lane * 8;
#pragma unroll
    for (int hh = 0; hh < 2; ++hh) {
      f4 a = *(const f4*)(rih + 4 * hh);
      W.w[g][0][2*hh+0] = h2{(_Float16)a[0], (_Float16)a[1]};
      W.w[g][0][2*hh+1] = h2{(_Float16)a[2], (_Float16)a[3]};
    }
    const float* rhh = w_hh + ((size_t)g * H_DIM + j) * H_DIM + lane * 8;
#pragma unroll
    for (int s = 1; s < 5; ++s) {
#pragma unroll
      for (int hh = 0; hh < 2; ++hh) {
        f4 a = *(const f4*)(rhh + (s - 1) * 512 + 4 * hh);
        W.w[g][s][2*hh+0] = h2{(_Float16)a[0], (_Float16)a[1]};
        W.w[g][s][2*hh+1] = h2{(_Float16)a[2], (_Float16)a[3]};
      }
    }
    W.bi[g] = b_ih[g * H_DIM + j];
    W.bh[g] = b_hh[g * H_DIM + j];
  }
}

// Tag-synchronized h staging: poll own 16B granule, drop f16 payloads to LDS.
__device__ __forceinline__ void stage4(_Float16* lbuf, const u32* p, u32 tag, int tid) {
  u32 v0, v1, v2, v3;
  poll_granule(p, tag, v0, v1, v2, v3);
  u64 pk = (u64)((v0 & 0xffffu) | (v1 << 16))
         | ((u64)((v2 & 0xffffu) | (v3 << 16)) << 32);
  *(u64*)(lbuf + tid * 4) = pk;
}

__device__ __forceinline__ void dot_h(const WRegs& W, const _Float16* lbuf, int lane,
                                      float& ar, float& az, float& anh) {
#pragma unroll
  for (int s = 1; s < 5; ++s) {
    H4 hh = *(const H4*)(lbuf + (s - 1) * 512 + lane * 8);
#pragma unroll
    for (int q = 0; q < 4; ++q) {
      ar  = fdot2_(W.w[0][s][q], hh.v[q], ar);
      az  = fdot2_(W.w[1][s][q], hh.v[q], az);
      anh = fdot2_(W.w[2][s][q], hh.v[q], anh);
    }
  }
}

__device__ __forceinline__ void wave_red4(float& a, float& b, float& c, float& d) {
#pragma unroll
  for (int off = 32; off > 0; off >>= 1) {
    a += __shfl_xor(a, off, 64);
    b += __shfl_xor(b, off, 64);
    c += __shfl_xor(c, off, 64);
    d += __shfl_xor(d, off, 64);
  }
}

__global__ void __launch_bounds__(NTHR, 2) rnn_persistent(
    const float* __restrict__ input_,
    const float* __restrict__ ewih, const float* __restrict__ ewhh,
    const float* __restrict__ ebih, const float* __restrict__ ebhh,
    const float* __restrict__ dwih, const float* __restrict__ dwhh,
    const float* __restrict__ dbih, const float* __restrict__ dbhh,
    const float* __restrict__ h2ow, const float* __restrict__ h2ob,
    float* __restrict__ out, char* __restrict__ ws, int tdec, int R)
{
  __shared__ alignas(16) _Float16 h_lds[2 * H_DIM];   // double buffer (parity of t)
  __shared__ float hred[8];
  __shared__ float redm[8], reds[8];
  __shared__ int   sidx[8];
  __shared__ int   idx_sh;

  u64* logits = (u64*)ws;
  u64* idxp   = (u64*)(ws + 4096);
  u32* gex    = (u32*)(ws + 8192);                 // replica 0 base

  const int tid  = threadIdx.x;
  const int lane = tid & 63;
  const int wid  = tid >> 6;
  const int blk  = blockIdx.x;
  const int j    = blk * 8 + wid;                  // hidden unit owned by this wave
  const u32* gexr = gex + (size_t)(blk & (R - 1)) * RSTR;  // replica this block polls

  WRegs W;
  load_weights(W, j, lane, ewih, ewhh, ebih, ebhh);
  float brz0 = W.bi[0] + W.bh[0];
  float brz1 = W.bi[1] + W.bh[1];

  float hold = 0.f;   // exact fp32 carry of h_j

  // ---------------- encoder ----------------
  // iter t: consume h(t) [tag t, slot t&3] from own replica; produce h(t+1)
  // into ALL replicas via ONE coalesced store instruction by wave 0 (8 x 32B
  // packets). memset gives {tag0,0.0f16} = valid h(0)=0 in every replica.
  for (u32 t = 0; t < L_SEQ; ++t) {
    _Float16* lbuf = h_lds + (t & 1) * H_DIM;
    const float* xr = input_ + (size_t)t * I_DIM + lane * 8;
    f4 xa = *(const f4*)xr;                  // prefetch; latency hides under poll
    f4 xb = *(const f4*)(xr + 4);

    stage4(lbuf, gexr + (t & (BUFS - 1)) * H_DIM + tid * 4, t & 0xffffu, tid);

    h2 xv[4] = { h2{(_Float16)xa[0], (_Float16)xa[1]}, h2{(_Float16)xa[2], (_Float16)xa[3]},
                 h2{(_Float16)xb[0], (_Float16)xb[1]}, h2{(_Float16)xb[2], (_Float16)xb[3]} };
    float ar = 0.f, az = 0.f, anx = 0.f, anh = 0.f;
#pragma unroll
    for (int q = 0; q < 4; ++q) {
      ar  = fdot2_(W.w[0][0][q], xv[q], ar);
      az  = fdot2_(W.w[1][0][q], xv[q], az);
      anx = fdot2_(W.w[2][0][q], xv[q], anx);
    }
    __syncthreads();

    dot_h(W, lbuf, lane, ar, az, anh);
    wave_red4(ar, az, anx, anh);

    float r = fast_sigmoid(ar + brz0);
    float z = fast_sigmoid(az + brz1);
    float n = fast_tanh(anx + W.bi[2] + r * (anh + W.bh[2]));
    hold = (1.f - z) * n + z * hold;

    // coalesced multicast: lane 8k+i of wave 0 stores word i of replica k
    if (lane == 0) hred[wid] = hold;
    __syncthreads();
    if (wid == 0) {
      const u32 tg = (t + 1) & 0xffffu;
      const u32 sl = (t + 1) & (BUFS - 1);
      const int rep = lane >> 3, wi = lane & 7;
      u32 pk = packh(tg, hred[wi]);
      if (rep < R)
        ASTORE32((u32*)gex + (size_t)rep * RSTR + sl * H_DIM + blk * 8 + wi, pk);
    }
  }

  // ---------------- decoder ----------------
  load_weights(W, j, lane, dwih, dwhh, dbih, dbhh);
  brz0 = W.bi[0] + W.bh[0];
  brz1 = W.bi[1] + W.bh[1];
  __syncthreads();

  for (int d = 0; d < tdec; ++d) {
    const u32 t = L_SEQ + (u32)d;
    _Float16* lbuf = h_lds + (t & 1) * H_DIM;

    if (tid == 0) {
      int ix = -1;
      if (d > 0) {                          // poll one-hot index {tag d}
        u64 pk = ALOAD64(idxp);
        while (tag64(pk) != (u32)d) { __builtin_amdgcn_s_sleep(1); pk = ALOAD64(idxp); }
        ix = (int)(u32)pk;
      }
      idx_sh = ix;
    }
    stage4(lbuf, gexr + (t & (BUFS - 1)) * H_DIM + tid * 4, t & 0xffffu, tid);
    __syncthreads();
    const int idx = idx_sh;

    float ar = 0.f, az = 0.f, anx = 0.f, anh = 0.f;
    if (idx >= 0 && lane == (idx >> 3)) {
      const int qq = (idx & 7) >> 1;
      const int pp = idx & 1;
#pragma unroll
      for (int q = 0; q < 4; ++q) if (q == qq) {
        ar  += pp ? (float)W.w[0][0][q][1] : (float)W.w[0][0][q][0];
        az  += pp ? (float)W.w[1][0][q][1] : (float)W.w[1][0][q][0];
        anx += pp ? (float)W.w[2][0][q][1] : (float)W.w[2][0][q][0];
      }
    }
    dot_h(W, lbuf, lane, ar, az, anh);
    wave_red4(ar, az, anx, anh);

    float r = fast_sigmoid(ar + brz0);
    float z = fast_sigmoid(az + brz1);
    float n = fast_tanh(anx + W.bi[2] + r * (anh + W.bh[2]));
    hold = (1.f - z) * n + z * hold;

    if (lane == 0) hred[wid] = hold;
    __syncthreads();
    if (wid == 0) {
      const u32 tg = (t + 1) & 0xffffu;
      const u32 sl = (t + 1) & (BUFS - 1);
      const int rep = lane >> 3, wi = lane & 7;
      u32 pk = packh(tg, hred[wi]);
      if (rep < R)
        ASTORE32((u32*)gex + (size_t)rep * RSTR + sl * H_DIM + blk * 8 + wi, pk);
    }

    // ---- logits: rows 2*blk, 2*blk+1; consume h(t+1) from own replica ----
    {
      const int row = 2 * blk + (tid >> 8);
      const int kk  = (tid & 255) * 8;
      const float* wrow = h2ow + (size_t)row * H_DIM + kk;
      f4 wa = *(const f4*)wrow, wb = *(const f4*)(wrow + 4);
      const u32* hp = gexr + ((t + 1) & (BUFS - 1)) * H_DIM + kk;
      const u32 htag = (t + 1) & 0xffffu;
      u32 g0, g1, g2, g3, g4, g5, g6, g7;
      poll_granule(hp,     htag, g0, g1, g2, g3);
      poll_granule(hp + 4, htag, g4, g5, g6, g7);
      float s = wa[0]*f16bits_to_f32(g0) + wa[1]*f16bits_to_f32(g1)
              + wa[2]*f16bits_to_f32(g2) + wa[3]*f16bits_to_f32(g3)
              + wb[0]*f16bits_to_f32(g4) + wb[1]*f16bits_to_f32(g5)
              + wb[2]*f16bits_to_f32(g6) + wb[3]*f16bits_to_f32(g7);
#pragma unroll
      for (int off = 32; off > 0; off >>= 1) s += __shfl_xor(s, off, 64);
      if (lane == 0) redm[wid] = s;
      __syncthreads();
      if (tid == 0)
        ASTORE64(&logits[2 * blk],
                 pack64((u32)(d + 1), redm[0] + redm[1] + redm[2] + redm[3] + h2ob[2 * blk]));
      if (tid == 256)
        ASTORE64(&logits[2 * blk + 1],
                 pack64((u32)(d + 1), redm[4] + redm[5] + redm[6] + redm[7] + h2ob[2 * blk + 1]));
    }
    __syncthreads();

    // ---- log-softmax + argmax on block 0 (consumes tagged logits) ----
    if (blk == 0) {
      u64 pk = ALOAD64(&logits[tid]);
      while (tag64(pk) != (u32)(d + 1)) { __builtin_amdgcn_s_sleep(1); pk = ALOAD64(&logits[tid]); }
      float v = val64(pk);
      float m = v; int mi = tid;
#pragma unroll
      for (int off = 32; off > 0; off >>= 1) {
        float om = __shfl_xor(m, off, 64);
        int   oi = __shfl_xor(mi, off, 64);
        if (om > m || (om == m && oi < mi)) { m = om; mi = oi; }
      }
      if (lane == 0) { redm[wid] = m; sidx[wid] = mi; }
      __syncthreads();
      float M = redm[0]; int MI = sidx[0];
#pragma unroll
      for (int w2 = 1; w2 < 8; ++w2)
        if (redm[w2] > M || (redm[w2] == M && sidx[w2] < MI)) { M = redm[w2]; MI = sidx[w2]; }
      float ss = __expf(v - M);
#pragma unroll
      for (int off = 32; off > 0; off >>= 1) ss += __shfl_xor(ss, off, 64);
      if (lane == 0) reds[wid] = ss;
      __syncthreads();
      float S = reds[0] + reds[1] + reds[2] + reds[3]
              + reds[4] + reds[5] + reds[6] + reds[7];
      out[(size_t)d * O_DIM + tid] = v - M - __logf(S);
      if (tid == 0)
        ASTORE64(idxp, pack64((u32)(d + 1), (u32)MI));
    }
    __syncthreads();   // LDS reuse guard (decoder only; negligible at 30 steps)
  }
}

extern "C" void kernel_launch(void* const* d_in, const int* in_sizes, int n_in,
                              void* d_out, int out_size, void* d_ws, size_t ws_size,
                              hipStream_t stream) {
  const float* input_ = (const float*)d_in[0];
  const float* ewih   = (const float*)d_in[1];
  const float* ewhh   = (const float*)d_in[2];
  const float* ebih   = (const float*)d_in[3];
  const float* ebhh   = (const float*)d_in[4];
  const float* dwih   = (const float*)d_in[5];
  const float* dwhh   = (const float*)d_in[6];
  const float* dbih   = (const float*)d_in[7];
  const float* dbhh   = (const float*)d_in[8];
  const float* h2ow   = (const float*)d_in[9];
  const float* h2ob   = (const float*)d_in[10];
  float* out = (float*)d_out;
  char*  ws  = (char*)d_ws;
  int tdec = out_size / O_DIM;   // 30

  // replica count from actual workspace size (R=1 degrades to the r3 design)
  int R = 1;
  if (ws_size >= 8192 + 32768) {
    size_t maxr = (ws_size - 8192) / 32768;
    while (R * 2 <= (int)(maxr < 8 ? maxr : 8)) R *= 2;
  }
  size_t zbytes = 8192 + (size_t)R * 32768;

  // zero logits+idx+replicas (tag0 == valid h(0)=0 in every replica)
  hipMemsetAsync(d_ws, 0, zbytes, stream);

  void* args[] = { (void*)&input_, (void*)&ewih, (void*)&ewhh, (void*)&ebih, (void*)&ebhh,
                   (void*)&dwih, (void*)&dwhh, (void*)&dbih, (void*)&dbhh,
                   (void*)&h2ow, (void*)&h2ob, (void*)&out, (void*)&ws, (void*)&tdec,
                   (void*)&R };
  hipLaunchCooperativeKernel((void*)rnn_persistent, dim3(NBLK), dim3(NTHR),
                             args, 0, stream);
}